// Round 10
// baseline (442.231 us; speedup 1.0000x reference)
//
#include <hip/hip_runtime.h>
#include <hip/hip_fp16.h>

#define NIMG   48
#define H      512
#define W      512
#define CH     32                       // output rows per block (512/32 = 16 chunks)
#define RCH    16
#define CCH    4
#define CW     128                      // cols per block
#define NTHR   64                       // 1 wave; 2 cols/thread; barriers ~free
#define LDSW   144                      // 138 needed (128 + 2*5 halo), pad
#define HT     42                       // h-rows per block (CH + 10)
#define NBLOCK (NIMG * RCH * CCH)       // 3072
#define NPIX   12582912.0f

__device__ __forceinline__ int refl(int x) {
    x = (x < 0) ? -x : x;
    return (x >= 512) ? (1022 - x) : x;
}

// Gaussian weights sigma=1.5, window 11.
static constexpr float GWc[11] = {
    0.00102838f, 0.00759876f, 0.03600075f, 0.10936075f, 0.21300700f,
    0.26601190f, 0.21300700f, 0.10936075f, 0.03600075f, 0.00759876f,
    0.00102838f};

__device__ __forceinline__ float ssim_from(__half2 M, __half2 E,
                                           float C1, float C2) {
    // M = {mu_s' (s centered: s = x1+x2-1), mu_d}; E = {blur(s'^2), blur(d^2)}
    const float mup = __low2float(M);
    const float mud = __high2float(M);
    const float esp = __low2float(E);
    const float ed  = __high2float(E);
    const float mus = mup + 1.0f;
    const float P   = mus * mus;
    const float Q   = mud * mud;
    const float Vs  = esp - mup * mup;
    const float Vd  = ed  - mud * mud;
    const float num = fmaf(0.5f, P - Q,  C1) * fmaf(0.5f, Vs - Vd, C2);
    const float den = fmaf(0.5f, P + Q,  C1) * fmaf(0.5f, Vs + Vd, C2);
    float s = num * __builtin_amdgcn_rcpf(den);
    return fminf(fmaxf(s, 0.f), 1.f);
}

__global__ __launch_bounds__(NTHR, 5)   // same budget that gave 40 VGPR / no spill in R5
void ssim_main(const float* __restrict__ img1, const float* __restrict__ img2,
               float* __restrict__ partial) {
    __shared__ __half2 sdl[11][LDSW];   // {s-1, d} per pixel, fp16 (one 11-row group)

    const int t     = threadIdx.x;
    const int xb    = blockIdx.x & 3;
    const int chunk = (blockIdx.x >> 2) & (RCH - 1);
    const int img   = blockIdx.x >> 6;
    const int C0    = xb * CW;
    const int R0    = chunk * CH;

    const float* __restrict__ b1 = img1 + (size_t)img * (H * W);
    const float* __restrict__ b2 = img2 + (size_t)img * (H * W);

    // Row-invariant staging columns (hoisted; refl computed once)
    const int gc0 = refl(C0 - 5 + t);
    const int gc1 = refl(C0 - 5 + t + 64);
    const bool l2 = t < 10;                       // lc = t+128 in [128,138)
    const int gc2 = l2 ? refl(C0 - 5 + t + 128) : 0;

    __half2 wh[11];
#pragma unroll
    for (int k = 0; k < 11; ++k) wh[k] = __float2half2_rn(GWc[k]);

    // 11 rotating slots x {A,B: mu col0/col1, C,D: E col0/col1}; slot = rr % 11.
    // dd==0 always initializes a slot before any accumulate -> no zero-init needed.
    __half2 pA[11], pB[11], pC[11], pD[11];

    float acc = 0.f;
    const float C1 = 0.0001f, C2 = 0.0009f;

#pragma unroll
    for (int grp = 0; grp < 4; ++grp) {           // groups of 11 h-rows: 11,11,11,9
        const int base  = grp * 11;
        const int nrows = (grp == 3) ? (HT - 33) : 11;
        __syncthreads();
        // ---- staging loop: KEPT ROLLED (bounds compiler load-hoisting; R8 lesson)
        for (int p = 0; p < nrows; ++p) {
            const int jr = refl(R0 - 5 + base + p);
            const float* r1 = b1 + jr * W;
            const float* r2 = b2 + jr * W;
            const float a0 = r1[gc0], b0 = r2[gc0];
            const float a1 = r1[gc1], b1v = r2[gc1];
            sdl[p][t]      = __floats2half2_rn(a0 + b0 - 1.0f, a0 - b0);
            sdl[p][t + 64] = __floats2half2_rn(a1 + b1v - 1.0f, a1 - b1v);
            if (l2) {
                const float a2 = r1[gc2], b2v = r2[gc2];
                sdl[p][t + 128] = __floats2half2_rn(a2 + b2v - 1.0f, a2 - b2v);
            }
        }
        __syncthreads();

        // ---- compute loop: fully unrolled, jj compile-time -> pruned scatter
#pragma unroll
        for (int p = 0; p < 11; ++p) {
            const int jj = base + p;              // compile-time h-row index
            if (jj < HT) {
                const float2* wp = (const float2*)(&sdl[p][2 * t]);
                float2 wr[6];
#pragma unroll
                for (int r = 0; r < 6; ++r) wr[r] = wp[r];
                __half2 sd[12];
#pragma unroll
                for (int r = 0; r < 6; ++r) {
                    sd[2 * r]     = __builtin_bit_cast(__half2, wr[r].x);
                    sd[2 * r + 1] = __builtin_bit_cast(__half2, wr[r].y);
                }
                __half2 sq[12];
#pragma unroll
                for (int j = 0; j < 12; ++j) sq[j] = __hmul2(sd[j], sd[j]);

                __half2 hM0 = __float2half2_rn(0.f), hE0 = hM0;
                __half2 hM1 = hM0, hE1 = hM0;
#pragma unroll
                for (int k = 0; k < 11; ++k) {
                    hM0 = __hfma2(wh[k], sd[k],     hM0);
                    hE0 = __hfma2(wh[k], sq[k],     hE0);
                    hM1 = __hfma2(wh[k], sd[k + 1], hM1);
                    hE1 = __hfma2(wh[k], sq[k + 1], hE1);
                }

                // ---- vertical scatter, pruned to live output rows rr in [0, CH)
#pragma unroll
                for (int dd = 0; dd <= 10; ++dd) {
                    const int rr = jj - dd;       // output row receiving GW[dd]
                    if (rr < 0 || rr >= CH) continue;   // compile-time pruning
                    const int s = rr % 11;
                    if (dd == 0) {
                        pA[s] = __hmul2(wh[0], hM0);
                        pB[s] = __hmul2(wh[0], hM1);
                        pC[s] = __hmul2(wh[0], hE0);
                        pD[s] = __hmul2(wh[0], hE1);
                    } else {
                        pA[s] = __hfma2(wh[dd], hM0, pA[s]);
                        pB[s] = __hfma2(wh[dd], hM1, pB[s]);
                        pC[s] = __hfma2(wh[dd], hE0, pC[s]);
                        pD[s] = __hfma2(wh[dd], hE1, pD[s]);
                    }
                    if (dd == 10) {               // row rr complete -> emit
                        acc += ssim_from(pA[s], pC[s], C1, C2);
                        acc += ssim_from(pB[s], pD[s], C1, C2);
                    }
                }
            }
        }
    }

    // ---- single-wave reduction
#pragma unroll
    for (int off = 32; off > 0; off >>= 1) acc += __shfl_xor(acc, off);
    if (t == 0) partial[blockIdx.x] = acc;
}

__global__ void ssim_finish(const float* __restrict__ partial, float* __restrict__ out) {
    float s = 0.f;
    for (int i = threadIdx.x; i < NBLOCK; i += 256) s += partial[i];
#pragma unroll
    for (int off = 32; off > 0; off >>= 1) s += __shfl_xor(s, off);
    __shared__ float wred[4];
    if ((threadIdx.x & 63) == 0) wred[threadIdx.x >> 6] = s;
    __syncthreads();
    if (threadIdx.x == 0)
        out[0] = 1.0f - (wred[0] + wred[1] + wred[2] + wred[3]) / NPIX;
}

extern "C" void kernel_launch(void* const* d_in, const int* in_sizes, int n_in,
                              void* d_out, int out_size, void* d_ws, size_t ws_size,
                              hipStream_t stream) {
    const float* img1 = (const float*)d_in[0];
    const float* img2 = (const float*)d_in[1];
    float* out = (float*)d_out;
    float* partial = (float*)d_ws;
    ssim_main<<<NBLOCK, NTHR, 0, stream>>>(img1, img2, partial);
    ssim_finish<<<1, 256, 0, stream>>>(partial, out);
}

// Round 11
// 164.601 us; speedup vs baseline: 2.6867x; 2.6867x over previous
//
#include <hip/hip_runtime.h>
#include <hip/hip_fp16.h>

#define NIMG   48
#define H      512
#define W      512
#define CH     32                       // output rows per block (512/32 = 16 chunks)
#define RCH    16
#define CCH    4
#define CW     128                      // cols per block
#define NTHR   64                       // 1 wave; 2 cols/thread
#define LDSW   144                      // 138 needed (128 + 2*5 halo), pad
#define HT     42                       // h-rows per block (CH + 10)
#define NBLOCK (NIMG * RCH * CCH)       // 3072
#define NPIX   12582912.0f

__device__ __forceinline__ int refl(int x) {
    x = (x < 0) ? -x : x;
    return (x >= 512) ? (1022 - x) : x;
}

// Gaussian weights sigma=1.5, window 11.
static constexpr float GWc[11] = {
    0.00102838f, 0.00759876f, 0.03600075f, 0.10936075f, 0.21300700f,
    0.26601190f, 0.21300700f, 0.10936075f, 0.03600075f, 0.00759876f,
    0.00102838f};

__device__ __forceinline__ float ssim_from(__half2 M, __half2 E,
                                           float C1, float C2) {
    // M = {mu_s' (s centered: s = x1+x2-1), mu_d}; E = {blur(s'^2), blur(d^2)}
    const float mup = __low2float(M);
    const float mud = __high2float(M);
    const float esp = __low2float(E);
    const float ed  = __high2float(E);
    const float mus = mup + 1.0f;
    const float P   = mus * mus;
    const float Q   = mud * mud;
    const float Vs  = esp - mup * mup;
    const float Vd  = ed  - mud * mud;
    const float num = fmaf(0.5f, P - Q,  C1) * fmaf(0.5f, Vs - Vd, C2);
    const float den = fmaf(0.5f, P + Q,  C1) * fmaf(0.5f, Vs + Vd, C2);
    float s = num * __builtin_amdgcn_rcpf(den);
    return fminf(fmaxf(s, 0.f), 1.f);
}

__global__ __launch_bounds__(NTHR, 5)   // R5-proven budget: 40 VGPR, no spills
void ssim_main(const float* __restrict__ img1, const float* __restrict__ img2,
               float* __restrict__ partial) {
    __shared__ __half2 sdl[11][LDSW];   // {s-1, d} per pixel, fp16

    const int t     = threadIdx.x;
    const int xb    = blockIdx.x & 3;
    const int chunk = (blockIdx.x >> 2) & (RCH - 1);
    const int img   = blockIdx.x >> 6;
    const int C0    = xb * CW;
    const int R0    = chunk * CH;

    const float* __restrict__ b1 = img1 + (size_t)img * (H * W);
    const float* __restrict__ b2 = img2 + (size_t)img * (H * W);

    // Row-invariant staging columns (hoisted)
    const int gc0 = refl(C0 - 5 + t);
    const int gc1 = refl(C0 - 5 + t + 64);
    const bool l2 = t < 10;                       // lc = t+128 in [128,138)
    const int gc2 = l2 ? refl(C0 - 5 + t + 128) : 0;

    __half2 wh[11];
#pragma unroll
    for (int k = 0; k < 11; ++k) wh[k] = __float2half2_rn(GWc[k]);

    // 11 slots x {A,B: mu col0/col1, C,D: E col0/col1}; slot index = (p - dd) mod 11.
    __half2 pA[11], pB[11], pC[11], pD[11];
#pragma unroll
    for (int i = 0; i < 11; ++i) {
        pA[i] = __float2half2_rn(0.f); pB[i] = pA[i];
        pC[i] = pA[i];                 pD[i] = pA[i];
    }

    float acc = 0.f;
    const float C1 = 0.0001f, C2 = 0.0009f;

    // Outer loop ROLLED (R8/R10 lesson: unrolling it causes cross-barrier
    // hoisting and catastrophic scratch spills). Groups of 11 h-rows: 11,11,11,9.
    for (int grp = 0; grp < 4; ++grp) {
        const int base  = grp * 11;
        const int nrows = (grp == 3) ? (HT - 33) : 11;
        __syncthreads();
        // staging loop: rolled
        for (int p = 0; p < nrows; ++p) {
            const int jr = refl(R0 - 5 + base + p);
            const float* r1 = b1 + jr * W;
            const float* r2 = b2 + jr * W;
            const float a0 = r1[gc0], b0 = r2[gc0];
            const float a1 = r1[gc1], b1v = r2[gc1];
            sdl[p][t]      = __floats2half2_rn(a0 + b0 - 1.0f, a0 - b0);
            sdl[p][t + 64] = __floats2half2_rn(a1 + b1v - 1.0f, a1 - b1v);
            if (l2) {
                const float a2 = r1[gc2], b2v = r2[gc2];
                sdl[p][t + 128] = __floats2half2_rn(a2 + b2v - 1.0f, a2 - b2v);
            }
        }
        __syncthreads();

        // inner compute loop: unrolled (dd compile-time), jj runtime
#pragma unroll
        for (int p = 0; p < 11; ++p) {
            const int jj = base + p;
            if (jj < HT) {
                const float2* wp = (const float2*)(&sdl[p][2 * t]);
                float2 wr[6];
#pragma unroll
                for (int r = 0; r < 6; ++r) wr[r] = wp[r];
                __half2 sd[12];
#pragma unroll
                for (int r = 0; r < 6; ++r) {
                    sd[2 * r]     = __builtin_bit_cast(__half2, wr[r].x);
                    sd[2 * r + 1] = __builtin_bit_cast(__half2, wr[r].y);
                }
                __half2 sq[12];
#pragma unroll
                for (int j = 0; j < 12; ++j) sq[j] = __hmul2(sd[j], sd[j]);

                __half2 hM0 = __float2half2_rn(0.f), hE0 = hM0;
                __half2 hM1 = hM0, hE1 = hM0;
#pragma unroll
                for (int k = 0; k < 11; ++k) {
                    hM0 = __hfma2(wh[k], sd[k],     hM0);
                    hE0 = __hfma2(wh[k], sq[k],     hE0);
                    hM1 = __hfma2(wh[k], sd[k + 1], hM1);
                    hE1 = __hfma2(wh[k], sq[k + 1], hE1);
                }

#pragma unroll
                for (int s_ = 0; s_ < 11; ++s_) {
                    const int dd = (p - s_ + 11) % 11;   // compile-time
                    if (dd == 0) {
                        pA[s_] = __hmul2(wh[0], hM0);
                        pB[s_] = __hmul2(wh[0], hM1);
                        pC[s_] = __hmul2(wh[0], hE0);
                        pD[s_] = __hmul2(wh[0], hE1);
                    } else if (dd == 10) {
                        if (jj >= 10) {                  // out row jj-10 in [0,CH)
                            const __half2 A  = __hfma2(wh[10], hM0, pA[s_]);
                            const __half2 B  = __hfma2(wh[10], hM1, pB[s_]);
                            const __half2 Cq = __hfma2(wh[10], hE0, pC[s_]);
                            const __half2 Dq = __hfma2(wh[10], hE1, pD[s_]);
                            acc += ssim_from(A, Cq, C1, C2);
                            acc += ssim_from(B, Dq, C1, C2);
                        }
                    } else {
                        pA[s_] = __hfma2(wh[dd], hM0, pA[s_]);
                        pB[s_] = __hfma2(wh[dd], hM1, pB[s_]);
                        pC[s_] = __hfma2(wh[dd], hE0, pC[s_]);
                        pD[s_] = __hfma2(wh[dd], hE1, pD[s_]);
                    }
                }
            }
        }
    }

    // ---- single-wave reduction
#pragma unroll
    for (int off = 32; off > 0; off >>= 1) acc += __shfl_xor(acc, off);
    if (t == 0) partial[blockIdx.x] = acc;
}

__global__ void ssim_finish(const float* __restrict__ partial, float* __restrict__ out) {
    float s = 0.f;
    for (int i = threadIdx.x; i < NBLOCK; i += 256) s += partial[i];
#pragma unroll
    for (int off = 32; off > 0; off >>= 1) s += __shfl_xor(s, off);
    __shared__ float wred[4];
    if ((threadIdx.x & 63) == 0) wred[threadIdx.x >> 6] = s;
    __syncthreads();
    if (threadIdx.x == 0)
        out[0] = 1.0f - (wred[0] + wred[1] + wred[2] + wred[3]) / NPIX;
}

extern "C" void kernel_launch(void* const* d_in, const int* in_sizes, int n_in,
                              void* d_out, int out_size, void* d_ws, size_t ws_size,
                              hipStream_t stream) {
    const float* img1 = (const float*)d_in[0];
    const float* img2 = (const float*)d_in[1];
    float* out = (float*)d_out;
    float* partial = (float*)d_ws;
    ssim_main<<<NBLOCK, NTHR, 0, stream>>>(img1, img2, partial);
    ssim_finish<<<1, 256, 0, stream>>>(partial, out);
}